// Round 6
// baseline (213.576 us; speedup 1.0000x reference)
//
#include <hip/hip_runtime.h>
#include <math.h>

// Problem constants
#define CC 384
#define DD 768
#define TT 32
#define NN 196
#define BB 16
#define KK 16
#define NSAMP 500
#define JV 18816          // N*C/4 (float4 groups per frame)
#define FRAME 75264       // N*C

__device__ __forceinline__ float gelu_exact(float x) {
    return 0.5f * x * (1.0f + erff(x * 0.70710678118654752440f));
}

// ---------------- Kernel 1: mean+max pool over N, fused LayerNorm ----------------
__global__ __launch_bounds__(384) void pool_kernel(const float* __restrict__ x,
                                                   const float* __restrict__ ln_g,
                                                   const float* __restrict__ ln_b,
                                                   float* __restrict__ xbar) {
    int row = blockIdx.x;                       // b*T + t
    const float4* xp = (const float4*)(x + (size_t)row * NN * CC);
    int tx = threadIdx.x;                       // 0..95
    int ty = threadIdx.y;                       // 0..3
    float4 s = make_float4(0.f, 0.f, 0.f, 0.f);
    float4 m = make_float4(-INFINITY, -INFINITY, -INFINITY, -INFINITY);
    for (int n = ty; n < NN; n += 4) {
        float4 v = xp[n * 96 + tx];
        s.x += v.x; s.y += v.y; s.z += v.z; s.w += v.w;
        m.x = fmaxf(m.x, v.x); m.y = fmaxf(m.y, v.y);
        m.z = fmaxf(m.z, v.z); m.w = fmaxf(m.w, v.w);
    }
    __shared__ float4 ssum[4][96];
    __shared__ float4 smax[4][96];
    __shared__ float xf[DD];
    ssum[ty][tx] = s;
    smax[ty][tx] = m;
    __syncthreads();
    if (ty == 0) {
        for (int r = 1; r < 4; ++r) {
            float4 a = ssum[r][tx];
            s.x += a.x; s.y += a.y; s.z += a.z; s.w += a.w;
            float4 b = smax[r][tx];
            m.x = fmaxf(m.x, b.x); m.y = fmaxf(m.y, b.y);
            m.z = fmaxf(m.z, b.z); m.w = fmaxf(m.w, b.w);
        }
        const float invn = 1.0f / (float)NN;
        xf[4*tx+0] = s.x * invn; xf[4*tx+1] = s.y * invn;
        xf[4*tx+2] = s.z * invn; xf[4*tx+3] = s.w * invn;
        xf[CC + 4*tx+0] = m.x; xf[CC + 4*tx+1] = m.y;
        xf[CC + 4*tx+2] = m.z; xf[CC + 4*tx+3] = m.w;
    }
    __syncthreads();
    int tid = ty * 96 + tx;                     // 0..383
    float e0 = xf[tid], e1 = xf[tid + CC];
    float ps = e0 + e1, pq = e0 * e0 + e1 * e1;
    #pragma unroll
    for (int off = 32; off; off >>= 1) {
        ps += __shfl_down(ps, off);
        pq += __shfl_down(pq, off);
    }
    __shared__ float red[12];
    __shared__ float mv[2];
    int wv = tid >> 6;
    if ((tid & 63) == 0) { red[wv] = ps; red[6 + wv] = pq; }
    __syncthreads();
    if (tid == 0) {
        float su = 0.f, sq = 0.f;
        #pragma unroll
        for (int i = 0; i < 6; ++i) { su += red[i]; sq += red[6 + i]; }
        float mean = su * (1.0f / DD);
        float var  = sq * (1.0f / DD) - mean * mean;
        mv[0] = mean;
        mv[1] = rsqrtf(var + 1e-5f);
    }
    __syncthreads();
    float mean = mv[0], inv = mv[1];
    float* o = xbar + (size_t)row * DD;
    o[tid]      = (e0 - mean) * inv * ln_g[tid]      + ln_b[tid];
    o[tid + CC] = (e1 - mean) * inv * ln_g[tid + CC] + ln_b[tid + CC];
}

// ---------------- Kernel 2: FC_in partial GEMM, split-K=8 ----------------
// grid (64 rowg[8], 3 colg[256], 8 kc[96]), 256 threads.
__global__ __launch_bounds__(256) void fcinA_kernel(const float* __restrict__ xbar,
                                                    const float* __restrict__ w_in,
                                                    float* __restrict__ pfc) {
    __shared__ float xs[8][96];
    int tid = threadIdx.x;
    int row0 = blockIdx.x * 8;
    int col  = blockIdx.y * 256 + tid;
    int k0   = blockIdx.z * 96;
    if (tid < 192) {                       // stage 8 rows x 96 = 192 float4
        int r = tid / 24, j = tid % 24;
        ((float4*)xs[r])[j] = *(const float4*)(xbar + (size_t)(row0 + r) * DD + k0 + 4 * j);
    }
    __syncthreads();

    float acc[8] = {0.f, 0.f, 0.f, 0.f, 0.f, 0.f, 0.f, 0.f};
    const float* wp = w_in + (size_t)k0 * DD + col;
    #pragma unroll 2
    for (int i = 0; i < 96; i += 4) {
        float w0 = wp[(size_t)(i + 0) * DD];
        float w1 = wp[(size_t)(i + 1) * DD];
        float w2 = wp[(size_t)(i + 2) * DD];
        float w3 = wp[(size_t)(i + 3) * DD];
        #pragma unroll
        for (int r = 0; r < 8; ++r) {
            float4 xv = *(const float4*)&xs[r][i];
            acc[r] += xv.x * w0 + xv.y * w1 + xv.z * w2 + xv.w * w3;
        }
    }
    float* o = pfc + ((size_t)blockIdx.z * 512 + row0) * DD + col;
    #pragma unroll
    for (int r = 0; r < 8; ++r) o[(size_t)r * DD] = acc[r];
}

// ---------------- Kernel 3: fused {combine h1 + mlp1A partials} and {gpool + global GEMM} ----
// grid 1056 blocks x 192 threads.
//   blocks [0,1024): mlp1A chunk (rowg = blk>>3, colg = (blk>>2)&1, kc = blk&3)
//   blocks [1024,1056): gpool chunk (q = blk-1024: b = q>>1, colg = q&1)
__global__ __launch_bounds__(192) void mid_kernel(const float* __restrict__ pfc,
                                                  const float* __restrict__ b_in,
                                                  const float* __restrict__ w1,
                                                  float* __restrict__ pm1,
                                                  float* __restrict__ G) {
    __shared__ float xs[4][96];
    __shared__ float gs[CC];
    int blk = blockIdx.x;
    int tid = threadIdx.x;

    if (blk < 1024) {
        int kc = blk & 3, colg = (blk >> 2) & 1, rowg = blk >> 3;
        int row0 = rowg * 4, col = colg * 192 + tid, k0 = kc * 96;
        // combine-on-read h1 local-half window: 4 rows x 96 k
        for (int e = tid; e < 384; e += 192) {
            int r = e / 96, kk = e % 96;
            int row = row0 + r, k = k0 + kk;
            float s = b_in[k];
            #pragma unroll
            for (int c8 = 0; c8 < 8; ++c8)
                s += pfc[((size_t)c8 * 512 + row) * DD + k];
            xs[r][kk] = gelu_exact(s);
        }
        __syncthreads();

        float acc[4] = {0.f, 0.f, 0.f, 0.f};
        const float* wp = w1 + (size_t)k0 * CC + col;
        #pragma unroll 2
        for (int i = 0; i < 96; i += 4) {
            float w0 = wp[(size_t)(i + 0) * CC];
            float w1v = wp[(size_t)(i + 1) * CC];
            float w2 = wp[(size_t)(i + 2) * CC];
            float w3 = wp[(size_t)(i + 3) * CC];
            #pragma unroll
            for (int r = 0; r < 4; ++r) {
                float4 xv = *(const float4*)&xs[r][i];
                acc[r] += xv.x * w0 + xv.y * w1v + xv.z * w2 + xv.w * w3;
            }
        }
        float* o = pm1 + ((size_t)kc * 512 + row0) * CC + col;
        #pragma unroll
        for (int r = 0; r < 4; ++r) o[(size_t)r * CC] = acc[r];
    } else {
        int q = blk - 1024;
        int b = q >> 1, colg = q & 1;
        // gs[i] = mean_t gelu(h1_global[b,t,i]) with combine-on-read
        for (int i = tid; i < CC; i += 192) {
            float bias = b_in[CC + i];
            float s = 0.f;
            for (int t = 0; t < TT; ++t) {
                float v = bias;
                #pragma unroll
                for (int c8 = 0; c8 < 8; ++c8)
                    v += pfc[((size_t)c8 * 512 + b * TT + t) * DD + CC + i];
                s += gelu_exact(v);
            }
            gs[i] = s * (1.0f / TT);
        }
        __syncthreads();
        int col = colg * 192 + tid;
        float acc = 0.f;
        const float* wp = w1 + (size_t)CC * CC + col;   // rows 384.. of w1
        #pragma unroll 8
        for (int i = 0; i < CC; ++i)
            acc += gs[i] * wp[(size_t)i * CC];
        G[b * CC + col] = acc;
    }
}

// ---------------- Kernel 4: fused h2-combine + mlp2 GEMM + scores + minmax + top-k ----------
// grid 16 blocks (one per batch) x 512 threads.
__global__ __launch_bounds__(512) void score_topk_kernel(const float* __restrict__ pm1,
                                                         const float* __restrict__ G,
                                                         const float* __restrict__ b1,
                                                         const float* __restrict__ w2,
                                                         const float* __restrict__ b2,
                                                         const float* __restrict__ w3,
                                                         const float* __restrict__ noise,
                                                         float* __restrict__ ind) {
    __shared__ float h2s[32][385];    // padded: r-stride 385 -> different banks
    __shared__ float srow[TT];
    __shared__ float ns[TT];
    __shared__ float mnmx[2];
    __shared__ int counts[KK * TT];
    int b = blockIdx.x, tid = threadIdx.x;

    counts[tid] = 0;
    // Build h2[b's 32 rows][384] = gelu(sum_kc pm1 + G + b1)
    for (int e = tid; e < 32 * CC; e += 512) {
        int r = e / CC, k = e % CC;
        int row = b * TT + r;
        float s = b1[k] + G[b * CC + k];
        #pragma unroll
        for (int kc = 0; kc < 4; ++kc)
            s += pm1[((size_t)kc * 512 + row) * CC + k];
        h2s[r][k] = gelu_exact(s);
    }
    __syncthreads();

    // mlp2: thread (r = tid>>4, ch = tid&15) computes cols [12ch, 12ch+12)
    {
        int r = tid >> 4, ch = tid & 15;
        float acc[12];
        #pragma unroll
        for (int j = 0; j < 12; ++j) acc[j] = 0.f;
        const float4* wq = (const float4*)w2;
        for (int k = 0; k < CC; ++k) {
            float hv = h2s[r][k];
            float4 wa = wq[k * 48 + ch * 3 + 0];
            float4 wb = wq[k * 48 + ch * 3 + 1];
            float4 wc = wq[k * 48 + ch * 3 + 2];
            acc[0] += hv * wa.x; acc[1] += hv * wa.y; acc[2]  += hv * wa.z; acc[3]  += hv * wa.w;
            acc[4] += hv * wb.x; acc[5] += hv * wb.y; acc[6]  += hv * wb.z; acc[7]  += hv * wb.w;
            acc[8] += hv * wc.x; acc[9] += hv * wc.y; acc[10] += hv * wc.z; acc[11] += hv * wc.w;
        }
        float part = 0.f;
        #pragma unroll
        for (int j = 0; j < 12; ++j) {
            int c = ch * 12 + j;
            part += gelu_exact(acc[j] + b2[c]) * w3[c];
        }
        #pragma unroll
        for (int off = 8; off; off >>= 1) part += __shfl_down(part, off);
        if (ch == 0) srow[r] = part;   // b3 omitted: cancels in min-max norm
    }
    __syncthreads();

    if (tid == 0) {
        float mn = srow[0], mx = srow[0];
        for (int t = 1; t < TT; ++t) { mn = fminf(mn, srow[t]); mx = fmaxf(mx, srow[t]); }
        mnmx[0] = mn; mnmx[1] = mx;
    }
    __syncthreads();
    if (tid < TT) ns[tid] = (srow[tid] - mnmx[0]) / (mnmx[1] - mnmx[0] + 1e-5f);
    __syncthreads();

    if (tid < NSAMP) {
        const float* nb = noise + ((size_t)b * NSAMP + tid) * TT;
        float p[TT];
        #pragma unroll
        for (int t = 0; t < TT; ++t) p[t] = ns[t] + nb[t] * 0.05f;
        int k = 0;
        #pragma unroll
        for (int t = 0; t < TT; ++t) {
            int rank = 0;
            #pragma unroll
            for (int u = 0; u < TT; ++u)
                rank += (p[u] > p[t] || (p[u] == p[t] && u < t)) ? 1 : 0;
            if (rank < KK) { atomicAdd(&counts[k * TT + t], 1); ++k; }
        }
    }
    __syncthreads();
    ind[b * (KK * TT) + tid] = (float)counts[tid] * (1.0f / NSAMP);
}

// ---------------- Kernel 5: weighted gather with active-frame compaction ----------------
__global__ __launch_bounds__(256) void gather_kernel(const float* __restrict__ x,
                                                     const float* __restrict__ ind,
                                                     float* __restrict__ out) {
    __shared__ float w[KK * TT];
    __shared__ int act[TT];
    __shared__ int nact_s;
    int b = blockIdx.y;
    int tid = threadIdx.x;
    w[tid] = ind[b * (KK * TT) + tid];
    w[256 + tid] = ind[b * (KK * TT) + 256 + tid];
    __syncthreads();
    if (tid == 0) {
        int n = 0;
        for (int t = 0; t < TT; ++t) {
            float s = 0.f;
            #pragma unroll
            for (int k = 0; k < KK; ++k) s += w[k * TT + t];
            if (s != 0.f) act[n++] = t;
        }
        nact_s = n;
    }
    __syncthreads();
    int nact = nact_s;

    int j4 = blockIdx.x * 256 + tid;
    if (j4 >= JV) return;

    const float4* xb = (const float4*)(x + (size_t)b * TT * FRAME);
    float4 acc[KK];
    #pragma unroll
    for (int k = 0; k < KK; ++k) acc[k] = make_float4(0.f, 0.f, 0.f, 0.f);

    for (int it = 0; it < nact; ++it) {
        int t = act[it];
        float4 v = xb[(size_t)t * JV + j4];
        #pragma unroll
        for (int k = 0; k < KK; ++k) {
            float wk = w[k * TT + t];
            acc[k].x += wk * v.x; acc[k].y += wk * v.y;
            acc[k].z += wk * v.z; acc[k].w += wk * v.w;
        }
    }
    float4* ob = (float4*)(out + (size_t)b * KK * FRAME);
    #pragma unroll
    for (int k = 0; k < KK; ++k)
        ob[(size_t)k * JV + j4] = acc[k];
}

extern "C" void kernel_launch(void* const* d_in, const int* in_sizes, int n_in,
                              void* d_out, int out_size, void* d_ws, size_t ws_size,
                              hipStream_t stream) {
    const float* x     = (const float*)d_in[0];
    const float* noise = (const float*)d_in[1];
    const float* ln_g  = (const float*)d_in[2];
    const float* ln_b  = (const float*)d_in[3];
    const float* w_in  = (const float*)d_in[4];
    const float* b_in  = (const float*)d_in[5];
    const float* w1    = (const float*)d_in[6];
    const float* b1    = (const float*)d_in[7];
    const float* w2    = (const float*)d_in[8];
    const float* b2    = (const float*)d_in[9];
    const float* w3    = (const float*)d_in[10];
    const float* b3    = (const float*)d_in[11];
    (void)b3;  // cancels in min-max normalization
    float* out = (float*)d_out;

    float* ws   = (float*)d_ws;
    float* xbar = ws;                        // 512*768 (LayerNorm'd)
    float* pfc  = xbar + 512 * DD;           // 8*512*768 partials
    float* pm1  = pfc + 8 * 512 * DD;        // 4*512*384 partials
    float* G    = pm1 + 4 * 512 * CC;        // 16*384
    float* ind  = G + BB * CC;               // 16*512

    hipLaunchKernelGGL(pool_kernel, dim3(BB * TT), dim3(96, 4), 0, stream,
                       x, ln_g, ln_b, xbar);
    hipLaunchKernelGGL(fcinA_kernel, dim3(64, 3, 8), dim3(256), 0, stream,
                       xbar, w_in, pfc);
    hipLaunchKernelGGL(mid_kernel, dim3(1056), dim3(192), 0, stream,
                       pfc, b_in, w1, pm1, G);
    hipLaunchKernelGGL(score_topk_kernel, dim3(BB), dim3(512), 0, stream,
                       pm1, G, b1, w2, b2, w3, noise, ind);
    hipLaunchKernelGGL(gather_kernel, dim3((JV + 255) / 256, BB), dim3(256), 0, stream,
                       x, ind, out);
}

// Round 7
// 164.955 us; speedup vs baseline: 1.2948x; 1.2948x over previous
//
#include <hip/hip_runtime.h>
#include <math.h>

// Problem constants
#define CC 384
#define DD 768
#define TT 32
#define NN 196
#define BB 16
#define KK 16
#define NSAMP 500
#define JV 18816          // N*C/4 (float4 groups per frame)
#define FRAME 75264       // N*C

__device__ __forceinline__ float gelu_exact(float x) {
    return 0.5f * x * (1.0f + erff(x * 0.70710678118654752440f));
}

// ---------------- Kernel 1: mean+max pool over N, fused LayerNorm ----------------
__global__ __launch_bounds__(384) void pool_kernel(const float* __restrict__ x,
                                                   const float* __restrict__ ln_g,
                                                   const float* __restrict__ ln_b,
                                                   float* __restrict__ xbar) {
    int row = blockIdx.x;                       // b*T + t
    const float4* xp = (const float4*)(x + (size_t)row * NN * CC);
    int tx = threadIdx.x;                       // 0..95
    int ty = threadIdx.y;                       // 0..3
    float4 s = make_float4(0.f, 0.f, 0.f, 0.f);
    float4 m = make_float4(-INFINITY, -INFINITY, -INFINITY, -INFINITY);
    for (int n = ty; n < NN; n += 4) {
        float4 v = xp[n * 96 + tx];
        s.x += v.x; s.y += v.y; s.z += v.z; s.w += v.w;
        m.x = fmaxf(m.x, v.x); m.y = fmaxf(m.y, v.y);
        m.z = fmaxf(m.z, v.z); m.w = fmaxf(m.w, v.w);
    }
    __shared__ float4 ssum[4][96];
    __shared__ float4 smax[4][96];
    __shared__ float xf[DD];
    ssum[ty][tx] = s;
    smax[ty][tx] = m;
    __syncthreads();
    if (ty == 0) {
        for (int r = 1; r < 4; ++r) {
            float4 a = ssum[r][tx];
            s.x += a.x; s.y += a.y; s.z += a.z; s.w += a.w;
            float4 b = smax[r][tx];
            m.x = fmaxf(m.x, b.x); m.y = fmaxf(m.y, b.y);
            m.z = fmaxf(m.z, b.z); m.w = fmaxf(m.w, b.w);
        }
        const float invn = 1.0f / (float)NN;
        xf[4*tx+0] = s.x * invn; xf[4*tx+1] = s.y * invn;
        xf[4*tx+2] = s.z * invn; xf[4*tx+3] = s.w * invn;
        xf[CC + 4*tx+0] = m.x; xf[CC + 4*tx+1] = m.y;
        xf[CC + 4*tx+2] = m.z; xf[CC + 4*tx+3] = m.w;
    }
    __syncthreads();
    int tid = ty * 96 + tx;                     // 0..383
    float e0 = xf[tid], e1 = xf[tid + CC];
    float ps = e0 + e1, pq = e0 * e0 + e1 * e1;
    #pragma unroll
    for (int off = 32; off; off >>= 1) {
        ps += __shfl_down(ps, off);
        pq += __shfl_down(pq, off);
    }
    __shared__ float red[12];
    __shared__ float mv[2];
    int wv = tid >> 6;
    if ((tid & 63) == 0) { red[wv] = ps; red[6 + wv] = pq; }
    __syncthreads();
    if (tid == 0) {
        float su = 0.f, sq = 0.f;
        #pragma unroll
        for (int i = 0; i < 6; ++i) { su += red[i]; sq += red[6 + i]; }
        float mean = su * (1.0f / DD);
        float var  = sq * (1.0f / DD) - mean * mean;
        mv[0] = mean;
        mv[1] = rsqrtf(var + 1e-5f);
    }
    __syncthreads();
    float mean = mv[0], inv = mv[1];
    float* o = xbar + (size_t)row * DD;
    o[tid]      = (e0 - mean) * inv * ln_g[tid]      + ln_b[tid];
    o[tid + CC] = (e1 - mean) * inv * ln_g[tid + CC] + ln_b[tid + CC];
}

// ---------------- Kernel 2: FC_in partial GEMM, split-K=8 ----------------
// grid (64 rowg[8], 3 colg[256], 8 kc[96]), 256 threads.
__global__ __launch_bounds__(256) void fcinA_kernel(const float* __restrict__ xbar,
                                                    const float* __restrict__ w_in,
                                                    float* __restrict__ pfc) {
    __shared__ float xs[8][96];
    int tid = threadIdx.x;
    int row0 = blockIdx.x * 8;
    int col  = blockIdx.y * 256 + tid;
    int k0   = blockIdx.z * 96;
    if (tid < 192) {                       // stage 8 rows x 96 = 192 float4
        int r = tid / 24, j = tid % 24;
        ((float4*)xs[r])[j] = *(const float4*)(xbar + (size_t)(row0 + r) * DD + k0 + 4 * j);
    }
    __syncthreads();

    float acc[8] = {0.f, 0.f, 0.f, 0.f, 0.f, 0.f, 0.f, 0.f};
    const float* wp = w_in + (size_t)k0 * DD + col;
    #pragma unroll 2
    for (int i = 0; i < 96; i += 4) {
        float w0 = wp[(size_t)(i + 0) * DD];
        float w1 = wp[(size_t)(i + 1) * DD];
        float w2 = wp[(size_t)(i + 2) * DD];
        float w3 = wp[(size_t)(i + 3) * DD];
        #pragma unroll
        for (int r = 0; r < 8; ++r) {
            float4 xv = *(const float4*)&xs[r][i];
            acc[r] += xv.x * w0 + xv.y * w1 + xv.z * w2 + xv.w * w3;
        }
    }
    float* o = pfc + ((size_t)blockIdx.z * 512 + row0) * DD + col;
    #pragma unroll
    for (int r = 0; r < 8; ++r) o[(size_t)r * DD] = acc[r];
}

// ---------------- Kernel 3: fused {combine h1 + mlp1A partials} and {gpool + global GEMM} ----
// grid 1056 blocks x 192 threads.
__global__ __launch_bounds__(192) void mid_kernel(const float* __restrict__ pfc,
                                                  const float* __restrict__ b_in,
                                                  const float* __restrict__ w1,
                                                  float* __restrict__ pm1,
                                                  float* __restrict__ G) {
    __shared__ float xs[4][96];
    __shared__ float gs[CC];
    int blk = blockIdx.x;
    int tid = threadIdx.x;

    if (blk < 1024) {
        int kc = blk & 3, colg = (blk >> 2) & 1, rowg = blk >> 3;
        int row0 = rowg * 4, col = colg * 192 + tid, k0 = kc * 96;
        for (int e = tid; e < 384; e += 192) {
            int r = e / 96, kk = e % 96;
            int row = row0 + r, k = k0 + kk;
            float s = b_in[k];
            #pragma unroll
            for (int c8 = 0; c8 < 8; ++c8)
                s += pfc[((size_t)c8 * 512 + row) * DD + k];
            xs[r][kk] = gelu_exact(s);
        }
        __syncthreads();

        float acc[4] = {0.f, 0.f, 0.f, 0.f};
        const float* wp = w1 + (size_t)k0 * CC + col;
        #pragma unroll 2
        for (int i = 0; i < 96; i += 4) {
            float w0 = wp[(size_t)(i + 0) * CC];
            float w1v = wp[(size_t)(i + 1) * CC];
            float w2 = wp[(size_t)(i + 2) * CC];
            float w3 = wp[(size_t)(i + 3) * CC];
            #pragma unroll
            for (int r = 0; r < 4; ++r) {
                float4 xv = *(const float4*)&xs[r][i];
                acc[r] += xv.x * w0 + xv.y * w1v + xv.z * w2 + xv.w * w3;
            }
        }
        float* o = pm1 + ((size_t)kc * 512 + row0) * CC + col;
        #pragma unroll
        for (int r = 0; r < 4; ++r) o[(size_t)r * CC] = acc[r];
    } else {
        int q = blk - 1024;
        int b = q >> 1, colg = q & 1;
        for (int i = tid; i < CC; i += 192) {
            float bias = b_in[CC + i];
            float s = 0.f;
            for (int t = 0; t < TT; ++t) {
                float v = bias;
                #pragma unroll
                for (int c8 = 0; c8 < 8; ++c8)
                    v += pfc[((size_t)c8 * 512 + b * TT + t) * DD + CC + i];
                s += gelu_exact(v);
            }
            gs[i] = s * (1.0f / TT);
        }
        __syncthreads();
        int col = colg * 192 + tid;
        float acc = 0.f;
        const float* wp = w1 + (size_t)CC * CC + col;   // rows 384.. of w1
        #pragma unroll 8
        for (int i = 0; i < CC; ++i)
            acc += gs[i] * wp[(size_t)i * CC];
        G[b * CC + col] = acc;
    }
}

// ---------------- Kernel 4: per-row h2-combine + mlp2 GEMM -> scores ----------------
// grid 512 (one (b,t) row per block), 192 threads.
__global__ __launch_bounds__(192) void score_kernel(const float* __restrict__ pm1,
                                                    const float* __restrict__ G,
                                                    const float* __restrict__ b1,
                                                    const float* __restrict__ w2,
                                                    const float* __restrict__ b2,
                                                    const float* __restrict__ w3,
                                                    float* __restrict__ scores) {
    __shared__ float h2row[CC];
    int row = blockIdx.x, tid = threadIdx.x;
    int b = row >> 5;

    for (int e = tid; e < CC; e += 192) {
        float s = b1[e] + G[b * CC + e];
        #pragma unroll
        for (int kc = 0; kc < 4; ++kc)
            s += pm1[((size_t)kc * 512 + row) * CC + e];
        h2row[e] = gelu_exact(s);
    }
    __syncthreads();

    float a = b2[tid];
    const float* wp = w2 + tid;
    #pragma unroll 8
    for (int k = 0; k < CC; ++k)
        a += h2row[k] * wp[(size_t)k * 192];        // LDS broadcast * coalesced w2
    float v = gelu_exact(a) * w3[tid];
    #pragma unroll
    for (int off = 32; off; off >>= 1) v += __shfl_down(v, off);
    __shared__ float red[3];
    if ((tid & 63) == 0) red[tid >> 6] = v;
    __syncthreads();
    if (tid == 0) scores[row] = red[0] + red[1] + red[2];  // b3 cancels in min-max
}

// ---------------- Kernel 5: min-max norm + perturbed top-k -> indicators ----------------
__global__ __launch_bounds__(512) void topk_kernel(const float* __restrict__ scores,
                                                   const float* __restrict__ noise,
                                                   float* __restrict__ ind) {
    __shared__ float ns[TT];
    __shared__ float mnmx[2];
    __shared__ int counts[KK * TT];
    int b = blockIdx.x, tid = threadIdx.x;

    if (tid < TT) ns[tid] = scores[b * TT + tid];
    counts[tid] = 0;
    __syncthreads();
    if (tid == 0) {
        float mn = ns[0], mx = ns[0];
        for (int t = 1; t < TT; ++t) { mn = fminf(mn, ns[t]); mx = fmaxf(mx, ns[t]); }
        mnmx[0] = mn; mnmx[1] = mx;
    }
    __syncthreads();
    if (tid < TT) ns[tid] = (ns[tid] - mnmx[0]) / (mnmx[1] - mnmx[0] + 1e-5f);
    __syncthreads();

    if (tid < NSAMP) {
        const float* nb = noise + ((size_t)b * NSAMP + tid) * TT;
        float p[TT];
        #pragma unroll
        for (int t = 0; t < TT; ++t) p[t] = ns[t] + nb[t] * 0.05f;
        int k = 0;
        #pragma unroll
        for (int t = 0; t < TT; ++t) {
            int rank = 0;
            #pragma unroll
            for (int u = 0; u < TT; ++u)
                rank += (p[u] > p[t] || (p[u] == p[t] && u < t)) ? 1 : 0;
            if (rank < KK) { atomicAdd(&counts[k * TT + t], 1); ++k; }
        }
    }
    __syncthreads();
    ind[b * (KK * TT) + tid] = (float)counts[tid] * (1.0f / NSAMP);
}

// ---------------- Kernel 6: weighted gather with active-frame compaction ----------------
__global__ __launch_bounds__(256) void gather_kernel(const float* __restrict__ x,
                                                     const float* __restrict__ ind,
                                                     float* __restrict__ out) {
    __shared__ float w[KK * TT];
    __shared__ int act[TT];
    __shared__ int nact_s;
    int b = blockIdx.y;
    int tid = threadIdx.x;
    w[tid] = ind[b * (KK * TT) + tid];
    w[256 + tid] = ind[b * (KK * TT) + 256 + tid];
    __syncthreads();
    if (tid == 0) {
        int n = 0;
        for (int t = 0; t < TT; ++t) {
            float s = 0.f;
            #pragma unroll
            for (int k = 0; k < KK; ++k) s += w[k * TT + t];
            if (s != 0.f) act[n++] = t;
        }
        nact_s = n;
    }
    __syncthreads();
    int nact = nact_s;

    int j4 = blockIdx.x * 256 + tid;
    if (j4 >= JV) return;

    const float4* xb = (const float4*)(x + (size_t)b * TT * FRAME);
    float4 acc[KK];
    #pragma unroll
    for (int k = 0; k < KK; ++k) acc[k] = make_float4(0.f, 0.f, 0.f, 0.f);

    for (int it = 0; it < nact; ++it) {
        int t = act[it];
        float4 v = xb[(size_t)t * JV + j4];
        #pragma unroll
        for (int k = 0; k < KK; ++k) {
            float wk = w[k * TT + t];
            acc[k].x += wk * v.x; acc[k].y += wk * v.y;
            acc[k].z += wk * v.z; acc[k].w += wk * v.w;
        }
    }
    float4* ob = (float4*)(out + (size_t)b * KK * FRAME);
    #pragma unroll
    for (int k = 0; k < KK; ++k)
        ob[(size_t)k * JV + j4] = acc[k];
}

extern "C" void kernel_launch(void* const* d_in, const int* in_sizes, int n_in,
                              void* d_out, int out_size, void* d_ws, size_t ws_size,
                              hipStream_t stream) {
    const float* x     = (const float*)d_in[0];
    const float* noise = (const float*)d_in[1];
    const float* ln_g  = (const float*)d_in[2];
    const float* ln_b  = (const float*)d_in[3];
    const float* w_in  = (const float*)d_in[4];
    const float* b_in  = (const float*)d_in[5];
    const float* w1    = (const float*)d_in[6];
    const float* b1    = (const float*)d_in[7];
    const float* w2    = (const float*)d_in[8];
    const float* b2    = (const float*)d_in[9];
    const float* w3    = (const float*)d_in[10];
    const float* b3    = (const float*)d_in[11];
    (void)b3;  // cancels in min-max normalization
    float* out = (float*)d_out;

    float* ws     = (float*)d_ws;
    float* xbar   = ws;                       // 512*768 (LayerNorm'd)
    float* pfc    = xbar + 512 * DD;          // 8*512*768 partials
    float* pm1    = pfc + 8 * 512 * DD;       // 4*512*384 partials
    float* G      = pm1 + 4 * 512 * CC;       // 16*384
    float* scores = G + BB * CC;              // 512
    float* ind    = scores + 512;             // 16*512

    hipLaunchKernelGGL(pool_kernel, dim3(BB * TT), dim3(96, 4), 0, stream,
                       x, ln_g, ln_b, xbar);
    hipLaunchKernelGGL(fcinA_kernel, dim3(64, 3, 8), dim3(256), 0, stream,
                       xbar, w_in, pfc);
    hipLaunchKernelGGL(mid_kernel, dim3(1056), dim3(192), 0, stream,
                       pfc, b_in, w1, pm1, G);
    hipLaunchKernelGGL(score_kernel, dim3(512), dim3(192), 0, stream,
                       pm1, G, b1, w2, b2, w3, scores);
    hipLaunchKernelGGL(topk_kernel, dim3(BB), dim3(512), 0, stream,
                       scores, noise, ind);
    hipLaunchKernelGGL(gather_kernel, dim3((JV + 255) / 256, BB), dim3(256), 0, stream,
                       x, ind, out);
}

// Round 8
// 152.719 us; speedup vs baseline: 1.3985x; 1.0801x over previous
//
#include <hip/hip_runtime.h>
#include <math.h>

// Problem constants
#define CC 384
#define DD 768
#define TT 32
#define NN 196
#define BB 16
#define KK 16
#define NSAMP 500
#define JV 18816          // N*C/4 (float4 groups per frame)
#define FRAME 75264       // N*C

__device__ __forceinline__ float gelu_exact(float x) {
    return 0.5f * x * (1.0f + erff(x * 0.70710678118654752440f));
}

// ---------------- Kernel 1: mean+max pool over N, fused LayerNorm ----------------
__global__ __launch_bounds__(384) void pool_kernel(const float* __restrict__ x,
                                                   const float* __restrict__ ln_g,
                                                   const float* __restrict__ ln_b,
                                                   float* __restrict__ xbar) {
    int row = blockIdx.x;                       // b*T + t
    const float4* xp = (const float4*)(x + (size_t)row * NN * CC);
    int tx = threadIdx.x;                       // 0..95
    int ty = threadIdx.y;                       // 0..3
    float4 s = make_float4(0.f, 0.f, 0.f, 0.f);
    float4 m = make_float4(-INFINITY, -INFINITY, -INFINITY, -INFINITY);
    for (int n = ty; n < NN; n += 4) {
        float4 v = xp[n * 96 + tx];
        s.x += v.x; s.y += v.y; s.z += v.z; s.w += v.w;
        m.x = fmaxf(m.x, v.x); m.y = fmaxf(m.y, v.y);
        m.z = fmaxf(m.z, v.z); m.w = fmaxf(m.w, v.w);
    }
    __shared__ float4 ssum[4][96];
    __shared__ float4 smax[4][96];
    __shared__ float xf[DD];
    ssum[ty][tx] = s;
    smax[ty][tx] = m;
    __syncthreads();
    if (ty == 0) {
        for (int r = 1; r < 4; ++r) {
            float4 a = ssum[r][tx];
            s.x += a.x; s.y += a.y; s.z += a.z; s.w += a.w;
            float4 b = smax[r][tx];
            m.x = fmaxf(m.x, b.x); m.y = fmaxf(m.y, b.y);
            m.z = fmaxf(m.z, b.z); m.w = fmaxf(m.w, b.w);
        }
        const float invn = 1.0f / (float)NN;
        xf[4*tx+0] = s.x * invn; xf[4*tx+1] = s.y * invn;
        xf[4*tx+2] = s.z * invn; xf[4*tx+3] = s.w * invn;
        xf[CC + 4*tx+0] = m.x; xf[CC + 4*tx+1] = m.y;
        xf[CC + 4*tx+2] = m.z; xf[CC + 4*tx+3] = m.w;
    }
    __syncthreads();
    int tid = ty * 96 + tx;                     // 0..383
    float e0 = xf[tid], e1 = xf[tid + CC];
    float ps = e0 + e1, pq = e0 * e0 + e1 * e1;
    #pragma unroll
    for (int off = 32; off; off >>= 1) {
        ps += __shfl_down(ps, off);
        pq += __shfl_down(pq, off);
    }
    __shared__ float red[12];
    __shared__ float mv[2];
    int wv = tid >> 6;
    if ((tid & 63) == 0) { red[wv] = ps; red[6 + wv] = pq; }
    __syncthreads();
    if (tid == 0) {
        float su = 0.f, sq = 0.f;
        #pragma unroll
        for (int i = 0; i < 6; ++i) { su += red[i]; sq += red[6 + i]; }
        float mean = su * (1.0f / DD);
        float var  = sq * (1.0f / DD) - mean * mean;
        mv[0] = mean;
        mv[1] = rsqrtf(var + 1e-5f);
    }
    __syncthreads();
    float mean = mv[0], inv = mv[1];
    float* o = xbar + (size_t)row * DD;
    o[tid]      = (e0 - mean) * inv * ln_g[tid]      + ln_b[tid];
    o[tid + CC] = (e1 - mean) * inv * ln_g[tid + CC] + ln_b[tid + CC];
}

// ---------------- Kernel 2: FC_in partial GEMM, split-K=8 ----------------
// grid (64 rowg[8], 3 colg[256], 8 kc[96]), 256 threads.
__global__ __launch_bounds__(256) void fcinA_kernel(const float* __restrict__ xbar,
                                                    const float* __restrict__ w_in,
                                                    float* __restrict__ pfc) {
    __shared__ float xs[8][96];
    int tid = threadIdx.x;
    int row0 = blockIdx.x * 8;
    int col  = blockIdx.y * 256 + tid;
    int k0   = blockIdx.z * 96;
    if (tid < 192) {                       // stage 8 rows x 96 = 192 float4
        int r = tid / 24, j = tid % 24;
        ((float4*)xs[r])[j] = *(const float4*)(xbar + (size_t)(row0 + r) * DD + k0 + 4 * j);
    }
    __syncthreads();

    float acc[8] = {0.f, 0.f, 0.f, 0.f, 0.f, 0.f, 0.f, 0.f};
    const float* wp = w_in + (size_t)k0 * DD + col;
    #pragma unroll 2
    for (int i = 0; i < 96; i += 4) {
        float w0 = wp[(size_t)(i + 0) * DD];
        float w1 = wp[(size_t)(i + 1) * DD];
        float w2 = wp[(size_t)(i + 2) * DD];
        float w3 = wp[(size_t)(i + 3) * DD];
        #pragma unroll
        for (int r = 0; r < 8; ++r) {
            float4 xv = *(const float4*)&xs[r][i];
            acc[r] += xv.x * w0 + xv.y * w1 + xv.z * w2 + xv.w * w3;
        }
    }
    float* o = pfc + ((size_t)blockIdx.z * 512 + row0) * DD + col;
    #pragma unroll
    for (int r = 0; r < 8; ++r) o[(size_t)r * DD] = acc[r];
}

// ---------------- Kernel 3: combine 8 partials + bias + GELU -> h1 ----------------
// grid 384, 256 threads; one float4 per thread over 512x768.
__global__ __launch_bounds__(256) void fcinB_kernel(const float* __restrict__ pfc,
                                                    const float* __restrict__ b_in,
                                                    float* __restrict__ h1) {
    int gid = blockIdx.x * 256 + threadIdx.x;   // 0..98303
    int row = gid / 192, c4 = gid % 192;
    const float4* p4 = (const float4*)pfc;
    float4 s = ((const float4*)b_in)[c4];
    #pragma unroll
    for (int kc = 0; kc < 8; ++kc) {
        float4 v = p4[((size_t)kc * 512 + row) * 192 + c4];
        s.x += v.x; s.y += v.y; s.z += v.z; s.w += v.w;
    }
    float4 r;
    r.x = gelu_exact(s.x); r.y = gelu_exact(s.y);
    r.z = gelu_exact(s.z); r.w = gelu_exact(s.w);
    ((float4*)h1)[(size_t)row * 192 + c4] = r;
}

// ---------------- Kernel 4: fused {mlp1A local-half partial GEMM} + {gpool + global GEMM} ----
// grid 1056 x 192 threads, both halves reading h1 directly (streaming).
//   blocks [0,1024): mlp1A chunk (kc = blk&3, colg = (blk>>2)&1, rowg = blk>>3)
//   blocks [1024,1056): gpool chunk (q: b = q>>1, colg = q&1)
__global__ __launch_bounds__(192) void midB_kernel(const float* __restrict__ h1,
                                                   const float* __restrict__ w1,
                                                   float* __restrict__ pm1,
                                                   float* __restrict__ G) {
    __shared__ float xs[4][96];
    __shared__ float gs[CC];
    int blk = blockIdx.x;
    int tid = threadIdx.x;

    if (blk < 1024) {
        int kc = blk & 3, colg = (blk >> 2) & 1, rowg = blk >> 3;
        int row0 = rowg * 4, col = colg * 192 + tid, k0 = kc * 96;
        if (tid < 96) {                        // 4 rows x 24 float4 from h1
            int r = tid / 24, j = tid % 24;
            ((float4*)xs[r])[j] = *(const float4*)(h1 + (size_t)(row0 + r) * DD + k0 + 4 * j);
        }
        __syncthreads();

        float acc[4] = {0.f, 0.f, 0.f, 0.f};
        const float* wp = w1 + (size_t)k0 * CC + col;
        #pragma unroll 2
        for (int i = 0; i < 96; i += 4) {
            float w0 = wp[(size_t)(i + 0) * CC];
            float w1v = wp[(size_t)(i + 1) * CC];
            float w2 = wp[(size_t)(i + 2) * CC];
            float w3 = wp[(size_t)(i + 3) * CC];
            #pragma unroll
            for (int r = 0; r < 4; ++r) {
                float4 xv = *(const float4*)&xs[r][i];
                acc[r] += xv.x * w0 + xv.y * w1v + xv.z * w2 + xv.w * w3;
            }
        }
        float* o = pm1 + ((size_t)kc * 512 + row0) * CC + col;
        #pragma unroll
        for (int r = 0; r < 4; ++r) o[(size_t)r * CC] = acc[r];
    } else {
        int q = blk - 1024;
        int b = q >> 1, colg = q & 1;
        const float* hb = h1 + (size_t)b * TT * DD + CC;
        for (int i = tid; i < CC; i += 192) {
            float s = 0.f;
            #pragma unroll 8
            for (int t = 0; t < TT; ++t) s += hb[(size_t)t * DD + i];
            gs[i] = s * (1.0f / TT);
        }
        __syncthreads();
        int col = colg * 192 + tid;
        float acc = 0.f;
        const float* wp = w1 + (size_t)CC * CC + col;   // rows 384.. of w1
        #pragma unroll 8
        for (int i = 0; i < CC; ++i)
            acc += gs[i] * wp[(size_t)i * CC];
        G[b * CC + col] = acc;
    }
}

// ---------------- Kernel 5: combine 4 partials + G + bias + GELU -> h2 ----------------
// grid 192, 256 threads; one float4 per thread over 512x384.
__global__ __launch_bounds__(256) void mlp1B_kernel(const float* __restrict__ pm1,
                                                    const float* __restrict__ G,
                                                    const float* __restrict__ b1,
                                                    float* __restrict__ h2) {
    int gid = blockIdx.x * 256 + threadIdx.x;   // 0..49151
    int row = gid / 96, c4 = gid % 96;
    int b = row >> 5;
    const float4* p4 = (const float4*)pm1;
    float4 s = ((const float4*)b1)[c4];
    float4 gv = ((const float4*)G)[b * 96 + c4];
    s.x += gv.x; s.y += gv.y; s.z += gv.z; s.w += gv.w;
    #pragma unroll
    for (int kc = 0; kc < 4; ++kc) {
        float4 v = p4[((size_t)kc * 512 + row) * 96 + c4];
        s.x += v.x; s.y += v.y; s.z += v.z; s.w += v.w;
    }
    float4 r;
    r.x = gelu_exact(s.x); r.y = gelu_exact(s.y);
    r.z = gelu_exact(s.z); r.w = gelu_exact(s.w);
    ((float4*)h2)[(size_t)row * 96 + c4] = r;
}

// ---------------- Kernel 6: per-row mlp2 GEMM -> scores ----------------
// grid 512 (one (b,t) row per block), 192 threads, h2 row staged in LDS.
__global__ __launch_bounds__(192) void score_kernel(const float* __restrict__ h2,
                                                    const float* __restrict__ w2,
                                                    const float* __restrict__ b2,
                                                    const float* __restrict__ w3,
                                                    float* __restrict__ scores) {
    __shared__ float h2row[CC];
    int row = blockIdx.x, tid = threadIdx.x;

    if (tid < 96)
        ((float4*)h2row)[tid] = ((const float4*)(h2 + (size_t)row * CC))[tid];
    __syncthreads();

    float a = b2[tid];
    const float* wp = w2 + tid;
    #pragma unroll 8
    for (int k = 0; k < CC; ++k)
        a += h2row[k] * wp[(size_t)k * 192];        // LDS broadcast * coalesced w2
    float v = gelu_exact(a) * w3[tid];
    #pragma unroll
    for (int off = 32; off; off >>= 1) v += __shfl_down(v, off);
    __shared__ float red[3];
    if ((tid & 63) == 0) red[tid >> 6] = v;
    __syncthreads();
    if (tid == 0) scores[row] = red[0] + red[1] + red[2];  // b3 cancels in min-max
}

// ---------------- Kernel 7: min-max norm + perturbed top-k -> indicators ----------------
__global__ __launch_bounds__(512) void topk_kernel(const float* __restrict__ scores,
                                                   const float* __restrict__ noise,
                                                   float* __restrict__ ind) {
    __shared__ float ns[TT];
    __shared__ float mnmx[2];
    __shared__ int counts[KK * TT];
    int b = blockIdx.x, tid = threadIdx.x;

    if (tid < TT) ns[tid] = scores[b * TT + tid];
    counts[tid] = 0;
    __syncthreads();
    if (tid == 0) {
        float mn = ns[0], mx = ns[0];
        for (int t = 1; t < TT; ++t) { mn = fminf(mn, ns[t]); mx = fmaxf(mx, ns[t]); }
        mnmx[0] = mn; mnmx[1] = mx;
    }
    __syncthreads();
    if (tid < TT) ns[tid] = (ns[tid] - mnmx[0]) / (mnmx[1] - mnmx[0] + 1e-5f);
    __syncthreads();

    if (tid < NSAMP) {
        const float* nb = noise + ((size_t)b * NSAMP + tid) * TT;
        float p[TT];
        #pragma unroll
        for (int t = 0; t < TT; ++t) p[t] = ns[t] + nb[t] * 0.05f;
        int k = 0;
        #pragma unroll
        for (int t = 0; t < TT; ++t) {
            int rank = 0;
            #pragma unroll
            for (int u = 0; u < TT; ++u)
                rank += (p[u] > p[t] || (p[u] == p[t] && u < t)) ? 1 : 0;
            if (rank < KK) { atomicAdd(&counts[k * TT + t], 1); ++k; }
        }
    }
    __syncthreads();
    ind[b * (KK * TT) + tid] = (float)counts[tid] * (1.0f / NSAMP);
}

// ---------------- Kernel 8: weighted gather with active-frame compaction ----------------
__global__ __launch_bounds__(256) void gather_kernel(const float* __restrict__ x,
                                                     const float* __restrict__ ind,
                                                     float* __restrict__ out) {
    __shared__ float w[KK * TT];
    __shared__ int act[TT];
    __shared__ int nact_s;
    int b = blockIdx.y;
    int tid = threadIdx.x;
    w[tid] = ind[b * (KK * TT) + tid];
    w[256 + tid] = ind[b * (KK * TT) + 256 + tid];
    __syncthreads();
    if (tid == 0) {
        int n = 0;
        for (int t = 0; t < TT; ++t) {
            float s = 0.f;
            #pragma unroll
            for (int k = 0; k < KK; ++k) s += w[k * TT + t];
            if (s != 0.f) act[n++] = t;
        }
        nact_s = n;
    }
    __syncthreads();
    int nact = nact_s;

    int j4 = blockIdx.x * 256 + tid;
    if (j4 >= JV) return;

    const float4* xb = (const float4*)(x + (size_t)b * TT * FRAME);
    float4 acc[KK];
    #pragma unroll
    for (int k = 0; k < KK; ++k) acc[k] = make_float4(0.f, 0.f, 0.f, 0.f);

    for (int it = 0; it < nact; ++it) {
        int t = act[it];
        float4 v = xb[(size_t)t * JV + j4];
        #pragma unroll
        for (int k = 0; k < KK; ++k) {
            float wk = w[k * TT + t];
            acc[k].x += wk * v.x; acc[k].y += wk * v.y;
            acc[k].z += wk * v.z; acc[k].w += wk * v.w;
        }
    }
    float4* ob = (float4*)(out + (size_t)b * KK * FRAME);
    #pragma unroll
    for (int k = 0; k < KK; ++k)
        ob[(size_t)k * JV + j4] = acc[k];
}

extern "C" void kernel_launch(void* const* d_in, const int* in_sizes, int n_in,
                              void* d_out, int out_size, void* d_ws, size_t ws_size,
                              hipStream_t stream) {
    const float* x     = (const float*)d_in[0];
    const float* noise = (const float*)d_in[1];
    const float* ln_g  = (const float*)d_in[2];
    const float* ln_b  = (const float*)d_in[3];
    const float* w_in  = (const float*)d_in[4];
    const float* b_in  = (const float*)d_in[5];
    const float* w1    = (const float*)d_in[6];
    const float* b1    = (const float*)d_in[7];
    const float* w2    = (const float*)d_in[8];
    const float* b2    = (const float*)d_in[9];
    const float* w3    = (const float*)d_in[10];
    const float* b3    = (const float*)d_in[11];
    (void)b3;  // cancels in min-max normalization
    float* out = (float*)d_out;

    float* ws     = (float*)d_ws;
    float* xbar   = ws;                       // 512*768 (LayerNorm'd)
    float* pfc    = xbar + 512 * DD;          // 8*512*768 partials
    float* h1     = pfc + 8 * 512 * DD;       // 512*768
    float* pm1    = h1 + 512 * DD;            // 4*512*384 partials
    float* h2     = pm1 + 4 * 512 * CC;       // 512*384
    float* G      = h2 + 512 * CC;            // 16*384
    float* scores = G + BB * CC;              // 512
    float* ind    = scores + 512;             // 16*512

    hipLaunchKernelGGL(pool_kernel, dim3(BB * TT), dim3(96, 4), 0, stream,
                       x, ln_g, ln_b, xbar);
    hipLaunchKernelGGL(fcinA_kernel, dim3(64, 3, 8), dim3(256), 0, stream,
                       xbar, w_in, pfc);
    hipLaunchKernelGGL(fcinB_kernel, dim3(384), dim3(256), 0, stream,
                       pfc, b_in, h1);
    hipLaunchKernelGGL(midB_kernel, dim3(1056), dim3(192), 0, stream,
                       h1, w1, pm1, G);
    hipLaunchKernelGGL(mlp1B_kernel, dim3(192), dim3(256), 0, stream,
                       pm1, G, b1, h2);
    hipLaunchKernelGGL(score_kernel, dim3(512), dim3(192), 0, stream,
                       h2, w2, b2, w3, scores);
    hipLaunchKernelGGL(topk_kernel, dim3(BB), dim3(512), 0, stream,
                       scores, noise, ind);
    hipLaunchKernelGGL(gather_kernel, dim3((JV + 255) / 256, BB), dim3(256), 0, stream,
                       x, ind, out);
}